// Round 1
// baseline (8750.772 us; speedup 1.0000x reference)
//
#include <hip/hip_runtime.h>
#include <hip/hip_bf16.h>
#include <cstdint>

#define DIM 128

// ---------------------------------------------------------------------------
// Detect whether edge_index arrived as int64 (upper 32-bit words all zero) or
// int32. Writes 1 to *flag for int64, 0 for int32. Runs every call (same work).
// ---------------------------------------------------------------------------
__global__ void detect_idx64(const unsigned* __restrict__ e, int* __restrict__ flag) {
    if (threadIdx.x == 0 && blockIdx.x == 0) {
        int is64 = 1;
        for (int i = 0; i < 32; ++i) {
            if (e[2 * i + 1] != 0u) { is64 = 0; break; }
        }
        *flag = is64;
    }
}

// ---------------------------------------------------------------------------
// Edge scatter: AGG[dst] += H[src]. One thread per (edge, 4-float chunk).
// AGG must be pre-initialized with H (GIN: h + sum of neighbors).
// ---------------------------------------------------------------------------
__global__ __launch_bounds__(256) void scatter_add(
    const unsigned* __restrict__ eidx, const float* __restrict__ H,
    float* __restrict__ AGG, int E, const int* __restrict__ flag)
{
    long long gid = (long long)blockIdx.x * 256 + threadIdx.x;
    int e = (int)(gid >> 5);
    if (e >= E) return;
    int c = (int)(gid & 31);
    int s, d;
    if (*flag) {  // int64 layout: little-endian pairs
        s = (int)eidx[2 * (size_t)e];
        d = (int)eidx[2 * ((size_t)E + (size_t)e)];
    } else {      // int32 layout
        s = (int)eidx[(size_t)e];
        d = (int)eidx[(size_t)E + (size_t)e];
    }
    float4 v = *(const float4*)(H + (size_t)s * DIM + c * 4);
    float* p = AGG + (size_t)d * DIM + c * 4;
    unsafeAtomicAdd(p + 0, v.x);
    unsafeAtomicAdd(p + 1, v.y);
    unsafeAtomicAdd(p + 2, v.z);
    unsafeAtomicAdd(p + 3, v.w);
}

// ---------------------------------------------------------------------------
// Fused GEMM: O = act(U @ W + bias), optional folded BatchNorm affine.
//   do_bn=1: y = dot*A + B with A = gamma*rsqrt(var+eps), B = (b1-mean)*A+beta
//   do_bn=0: y = dot + bias
// ReLU always applied.
// Block: 256 threads -> 64 rows x 128 cols. Thread: 8 rows x 4 cols.
// W (64 KB fp32) staged in LDS; u rows read from global (broadcast, L1-hot).
// ---------------------------------------------------------------------------
__global__ __launch_bounds__(256) void gemm_fused(
    const float* __restrict__ U, const float* __restrict__ W,
    const float* __restrict__ bias,
    const float* __restrict__ gamma, const float* __restrict__ beta,
    const float* __restrict__ rmean, const float* __restrict__ rvar,
    float* __restrict__ O, int M, int do_bn)
{
    __shared__ float Ws[DIM * DIM];  // 64 KB
    const int t = threadIdx.x;
    const int row0 = blockIdx.x * 64;

    // Stage W into LDS: 4096 float4, 16 per thread, fully coalesced.
    {
        const float4* Wg = (const float4*)W;
        float4* Wl = (float4*)Ws;
        #pragma unroll
        for (int i = 0; i < 16; ++i) Wl[t + 256 * i] = Wg[t + 256 * i];
    }
    __syncthreads();

    const int tx = t & 31;        // column group: cols [tx*4, tx*4+4)
    const int ty = t >> 5;        // row group:   rows [ty*8, ty*8+8)
    const int col0 = tx * 4;

    const float* urow[8];
    #pragma unroll
    for (int i = 0; i < 8; ++i) {
        int gr = row0 + ty * 8 + i;
        urow[i] = U + (size_t)(gr < M ? gr : 0) * DIM;  // clamp; store guarded below
    }

    float acc[8][4];
    #pragma unroll
    for (int i = 0; i < 8; ++i)
        #pragma unroll
        for (int j = 0; j < 4; ++j) acc[i][j] = 0.0f;

    #pragma unroll 4
    for (int k = 0; k < DIM; k += 4) {
        float4 w0 = *(const float4*)&Ws[(k + 0) * DIM + col0];
        float4 w1 = *(const float4*)&Ws[(k + 1) * DIM + col0];
        float4 w2 = *(const float4*)&Ws[(k + 2) * DIM + col0];
        float4 w3 = *(const float4*)&Ws[(k + 3) * DIM + col0];
        #pragma unroll
        for (int i = 0; i < 8; ++i) {
            float4 u = *(const float4*)(urow[i] + k);
            acc[i][0] += u.x * w0.x + u.y * w1.x + u.z * w2.x + u.w * w3.x;
            acc[i][1] += u.x * w0.y + u.y * w1.y + u.z * w2.y + u.w * w3.y;
            acc[i][2] += u.x * w0.z + u.y * w1.z + u.z * w2.z + u.w * w3.z;
            acc[i][3] += u.x * w0.w + u.y * w1.w + u.z * w2.w + u.w * w3.w;
        }
    }

    // Per-column affine (BN folded) + ReLU
    float A[4], B[4];
    #pragma unroll
    for (int j = 0; j < 4; ++j) {
        int c = col0 + j;
        if (do_bn) {
            float s = gamma[c] * rsqrtf(rvar[c] + 1e-5f);
            A[j] = s;
            B[j] = (bias[c] - rmean[c]) * s + beta[c];
        } else {
            A[j] = 1.0f;
            B[j] = bias[c];
        }
    }

    #pragma unroll
    for (int i = 0; i < 8; ++i) {
        int gr = row0 + ty * 8 + i;
        if (gr < M) {
            float4 o;
            o.x = fmaxf(acc[i][0] * A[0] + B[0], 0.0f);
            o.y = fmaxf(acc[i][1] * A[1] + B[1], 0.0f);
            o.z = fmaxf(acc[i][2] * A[2] + B[2], 0.0f);
            o.w = fmaxf(acc[i][3] * A[3] + B[3], 0.0f);
            *(float4*)(O + (size_t)gr * DIM + col0) = o;
        }
    }
}

// ---------------------------------------------------------------------------
// Row-wise log_softmax over 128 cols. One wave (64 lanes) per row, 2 elems/lane.
// ---------------------------------------------------------------------------
__global__ __launch_bounds__(256) void log_softmax_k(
    const float* __restrict__ H, float* __restrict__ O, int M)
{
    int gid = blockIdx.x * 256 + threadIdx.x;
    int row = gid >> 6;
    int lane = threadIdx.x & 63;
    if (row >= M) return;
    float2 hv = *(const float2*)(H + (size_t)row * DIM + lane * 2);
    float m = fmaxf(hv.x, hv.y);
    #pragma unroll
    for (int off = 32; off > 0; off >>= 1) m = fmaxf(m, __shfl_xor(m, off));
    float s = __expf(hv.x - m) + __expf(hv.y - m);
    #pragma unroll
    for (int off = 32; off > 0; off >>= 1) s += __shfl_xor(s, off);
    float lse = m + __logf(s);
    float2 o;
    o.x = hv.x - lse;
    o.y = hv.y - lse;
    *(float2*)(O + (size_t)row * DIM + lane * 2) = o;
}

// ---------------------------------------------------------------------------
extern "C" void kernel_launch(void* const* d_in, const int* in_sizes, int n_in,
                              void* d_out, int out_size, void* d_ws, size_t ws_size,
                              hipStream_t stream) {
    const float*    x     = (const float*)d_in[0];
    const unsigned* eidx  = (const unsigned*)d_in[1];
    const float*    W1    = (const float*)d_in[2];
    const float*    b1    = (const float*)d_in[3];
    const float*    gamma = (const float*)d_in[4];
    const float*    beta  = (const float*)d_in[5];
    const float*    rmean = (const float*)d_in[6];
    const float*    rvar  = (const float*)d_in[7];
    const float*    W2    = (const float*)d_in[8];
    const float*    b2    = (const float*)d_in[9];

    const int M = in_sizes[0] / DIM;        // 100000
    const int E = in_sizes[1] / 2;          // 1600000
    const size_t hbytes = (size_t)M * DIM * sizeof(float);

    float* out  = (float*)d_out;
    char*  ws   = (char*)d_ws;
    int*   flag = (int*)ws;
    float* WSB  = (float*)(ws + 256);       // one h-sized scratch buffer

    detect_idx64<<<1, 64, 0, stream>>>(eidx, flag);

    // Ping-pong between WSB and d_out (d_out used as scratch; final
    // log_softmax writes it last).
    float* bufA = WSB;   // agg buffer for layer 0
    float* bufB = out;

    const int scatter_blocks = (int)(((long long)E * 32 + 255) / 256);
    const int gemm_blocks    = (M + 63) / 64;
    const int ls_blocks      = (M * 64 + 255) / 256;

    const float* h = x;
    for (int l = 0; l < 3; ++l) {
        // agg = h (copy), then agg += sum of neighbor features
        hipMemcpyAsync(bufA, h, hbytes, hipMemcpyDeviceToDevice, stream);
        scatter_add<<<scatter_blocks, 256, 0, stream>>>(eidx, h, bufA, E, flag);
        // h1 = relu(bn(agg @ W1 + b1))
        gemm_fused<<<gemm_blocks, 256, 0, stream>>>(
            bufA, W1 + (size_t)l * DIM * DIM, b1 + (size_t)l * DIM,
            gamma + (size_t)l * DIM, beta + (size_t)l * DIM,
            rmean + (size_t)l * DIM, rvar + (size_t)l * DIM,
            bufB, M, 1);
        // h2 = relu(h1 @ W2 + b2)
        gemm_fused<<<gemm_blocks, 256, 0, stream>>>(
            bufB, W2 + (size_t)l * DIM * DIM, b2 + (size_t)l * DIM,
            nullptr, nullptr, nullptr, nullptr,
            bufA, M, 0);
        h = bufA;
        float* tmp = bufA; bufA = bufB; bufB = tmp;
    }
    // h now points at the layer-3 output (in WSB after the final swap pattern:
    // l=2 wrote its result into the buffer h references; log_softmax -> d_out)
    log_softmax_k<<<ls_blocks, 256, 0, stream>>>(h, out, M);
}

// Round 2
// 1304.131 us; speedup vs baseline: 6.7100x; 6.7100x over previous
//
#include <hip/hip_runtime.h>
#include <hip/hip_bf16.h>
#include <cstdint>

#define DIM 128

// ---------------------------------------------------------------------------
// Detect whether edge_index arrived as int64 (upper 32-bit words all zero) or
// int32. Writes 1 to *flag for int64, 0 for int32. Runs every call.
// ---------------------------------------------------------------------------
__global__ void detect_idx64(const unsigned* __restrict__ e, int* __restrict__ flag) {
    if (threadIdx.x == 0 && blockIdx.x == 0) {
        int is64 = 1;
        for (int i = 0; i < 32; ++i) {
            if (e[2 * i + 1] != 0u) { is64 = 0; break; }
        }
        *flag = is64;
    }
}

__device__ __forceinline__ void load_edge(const unsigned* __restrict__ eidx,
                                          int e, int E, int is64,
                                          int& s, int& d) {
    if (is64) {
        s = (int)eidx[2 * (size_t)e];
        d = (int)eidx[2 * ((size_t)E + (size_t)e)];
    } else {
        s = (int)eidx[(size_t)e];
        d = (int)eidx[(size_t)E + (size_t)e];
    }
}

// ---------------------------- CSR construction -----------------------------
__global__ __launch_bounds__(256) void hist_dst(
    const unsigned* __restrict__ eidx, int* __restrict__ deg, int E,
    const int* __restrict__ flag)
{
    int e = blockIdx.x * 256 + threadIdx.x;
    if (e >= E) return;
    int s, d;
    load_edge(eidx, e, E, *flag, s, d);
    atomicAdd(&deg[d], 1);
}

// Per-block inclusive scan of 256 elements; writes partial scan to off[i+1],
// block total to bsum[blk].
__global__ __launch_bounds__(256) void scan_block(
    const int* __restrict__ deg, int* __restrict__ off,
    int* __restrict__ bsum, int N)
{
    __shared__ int sh[256];
    int t = threadIdx.x;
    int i = blockIdx.x * 256 + t;
    int v = (i < N) ? deg[i] : 0;
    sh[t] = v;
    __syncthreads();
    #pragma unroll
    for (int ofs = 1; ofs < 256; ofs <<= 1) {
        int add = (t >= ofs) ? sh[t - ofs] : 0;
        __syncthreads();
        sh[t] += add;
        __syncthreads();
    }
    if (i < N) off[i + 1] = sh[t];
    if (t == 255) bsum[blockIdx.x] = sh[255];
}

__global__ void scan_sums(const int* __restrict__ bsum,
                          int* __restrict__ bscan, int nblk)
{
    if (threadIdx.x == 0 && blockIdx.x == 0) {
        int run = 0;
        for (int b = 0; b < nblk; ++b) { run += bsum[b]; bscan[b] = run; }
    }
}

__global__ __launch_bounds__(256) void scan_add(
    const int* __restrict__ deg, int* __restrict__ off,
    int* __restrict__ pos, const int* __restrict__ bscan, int N)
{
    int i = blockIdx.x * 256 + threadIdx.x;
    if (i == 0) off[0] = 0;
    if (i >= N) return;
    int base = (blockIdx.x > 0) ? bscan[blockIdx.x - 1] : 0;
    int incl = off[i + 1] + base;
    off[i + 1] = incl;
    pos[i] = incl - deg[i];
}

__global__ __launch_bounds__(256) void fill_csr(
    const unsigned* __restrict__ eidx, int* __restrict__ pos,
    int* __restrict__ csr, int E, const int* __restrict__ flag)
{
    int e = blockIdx.x * 256 + threadIdx.x;
    if (e >= E) return;
    int s, d;
    load_edge(eidx, e, E, *flag, s, d);
    int slot = atomicAdd(&pos[d], 1);
    csr[slot] = s;
}

// ---------------------------------------------------------------------------
// CSR gather: AGG[d] = H[d] + sum_{s in N(d)} H[s]. One wave per node,
// 2 floats per lane. Output row written exactly once (no atomics).
// ---------------------------------------------------------------------------
__global__ __launch_bounds__(256) void gather_sum(
    const float* __restrict__ H, const int* __restrict__ off,
    const int* __restrict__ csr, float* __restrict__ AGG, int M)
{
    int node = (blockIdx.x * 256 + threadIdx.x) >> 6;
    int lane = threadIdx.x & 63;
    if (node >= M) return;
    int beg = off[node], end = off[node + 1];
    float2 acc = *(const float2*)(H + (size_t)node * DIM + lane * 2);
    for (int j = beg; j < end; ++j) {
        int s = csr[j];
        float2 v = *(const float2*)(H + (size_t)s * DIM + lane * 2);
        acc.x += v.x;
        acc.y += v.y;
    }
    *(float2*)(AGG + (size_t)node * DIM + lane * 2) = acc;
}

// ------------------------- Fallback: atomic scatter ------------------------
__global__ __launch_bounds__(256) void scatter_add(
    const unsigned* __restrict__ eidx, const float* __restrict__ H,
    float* __restrict__ AGG, int E, const int* __restrict__ flag)
{
    long long gid = (long long)blockIdx.x * 256 + threadIdx.x;
    int e = (int)(gid >> 5);
    if (e >= E) return;
    int c = (int)(gid & 31);
    int s, d;
    load_edge(eidx, e, E, *flag, s, d);
    float4 v = *(const float4*)(H + (size_t)s * DIM + c * 4);
    float* p = AGG + (size_t)d * DIM + c * 4;
    unsafeAtomicAdd(p + 0, v.x);
    unsafeAtomicAdd(p + 1, v.y);
    unsafeAtomicAdd(p + 2, v.z);
    unsafeAtomicAdd(p + 3, v.w);
}

// ---------------------------------------------------------------------------
// Fused GEMM: O = relu((U @ W + bias) affine). W staged in LDS (64 KB).
// Block: 256 threads -> 64 rows x 128 cols. Thread: 8 rows x 4 cols.
// ---------------------------------------------------------------------------
__global__ __launch_bounds__(256) void gemm_fused(
    const float* __restrict__ U, const float* __restrict__ W,
    const float* __restrict__ bias,
    const float* __restrict__ gamma, const float* __restrict__ beta,
    const float* __restrict__ rmean, const float* __restrict__ rvar,
    float* __restrict__ O, int M, int do_bn)
{
    __shared__ float Ws[DIM * DIM];
    const int t = threadIdx.x;
    const int row0 = blockIdx.x * 64;

    {
        const float4* Wg = (const float4*)W;
        float4* Wl = (float4*)Ws;
        #pragma unroll
        for (int i = 0; i < 16; ++i) Wl[t + 256 * i] = Wg[t + 256 * i];
    }
    __syncthreads();

    const int tx = t & 31;
    const int ty = t >> 5;
    const int col0 = tx * 4;

    const float* urow[8];
    #pragma unroll
    for (int i = 0; i < 8; ++i) {
        int gr = row0 + ty * 8 + i;
        urow[i] = U + (size_t)(gr < M ? gr : 0) * DIM;
    }

    float acc[8][4];
    #pragma unroll
    for (int i = 0; i < 8; ++i)
        #pragma unroll
        for (int j = 0; j < 4; ++j) acc[i][j] = 0.0f;

    #pragma unroll 4
    for (int k = 0; k < DIM; k += 4) {
        float4 w0 = *(const float4*)&Ws[(k + 0) * DIM + col0];
        float4 w1 = *(const float4*)&Ws[(k + 1) * DIM + col0];
        float4 w2 = *(const float4*)&Ws[(k + 2) * DIM + col0];
        float4 w3 = *(const float4*)&Ws[(k + 3) * DIM + col0];
        #pragma unroll
        for (int i = 0; i < 8; ++i) {
            float4 u = *(const float4*)(urow[i] + k);
            acc[i][0] += u.x * w0.x + u.y * w1.x + u.z * w2.x + u.w * w3.x;
            acc[i][1] += u.x * w0.y + u.y * w1.y + u.z * w2.y + u.w * w3.y;
            acc[i][2] += u.x * w0.z + u.y * w1.z + u.z * w2.z + u.w * w3.z;
            acc[i][3] += u.x * w0.w + u.y * w1.w + u.z * w2.w + u.w * w3.w;
        }
    }

    float A[4], B[4];
    #pragma unroll
    for (int j = 0; j < 4; ++j) {
        int c = col0 + j;
        if (do_bn) {
            float s = gamma[c] * rsqrtf(rvar[c] + 1e-5f);
            A[j] = s;
            B[j] = (bias[c] - rmean[c]) * s + beta[c];
        } else {
            A[j] = 1.0f;
            B[j] = bias[c];
        }
    }

    #pragma unroll
    for (int i = 0; i < 8; ++i) {
        int gr = row0 + ty * 8 + i;
        if (gr < M) {
            float4 o;
            o.x = fmaxf(acc[i][0] * A[0] + B[0], 0.0f);
            o.y = fmaxf(acc[i][1] * A[1] + B[1], 0.0f);
            o.z = fmaxf(acc[i][2] * A[2] + B[2], 0.0f);
            o.w = fmaxf(acc[i][3] * A[3] + B[3], 0.0f);
            *(float4*)(O + (size_t)gr * DIM + col0) = o;
        }
    }
}

// ---------------------------------------------------------------------------
__global__ __launch_bounds__(256) void log_softmax_k(
    const float* __restrict__ H, float* __restrict__ O, int M)
{
    int gid = blockIdx.x * 256 + threadIdx.x;
    int row = gid >> 6;
    int lane = threadIdx.x & 63;
    if (row >= M) return;
    float2 hv = *(const float2*)(H + (size_t)row * DIM + lane * 2);
    float m = fmaxf(hv.x, hv.y);
    #pragma unroll
    for (int off = 32; off > 0; off >>= 1) m = fmaxf(m, __shfl_xor(m, off));
    float s = __expf(hv.x - m) + __expf(hv.y - m);
    #pragma unroll
    for (int off = 32; off > 0; off >>= 1) s += __shfl_xor(s, off);
    float lse = m + __logf(s);
    float2 o;
    o.x = hv.x - lse;
    o.y = hv.y - lse;
    *(float2*)(O + (size_t)row * DIM + lane * 2) = o;
}

// ---------------------------------------------------------------------------
static inline size_t align256(size_t v) { return (v + 255) & ~(size_t)255; }

extern "C" void kernel_launch(void* const* d_in, const int* in_sizes, int n_in,
                              void* d_out, int out_size, void* d_ws, size_t ws_size,
                              hipStream_t stream) {
    const float*    x     = (const float*)d_in[0];
    const unsigned* eidx  = (const unsigned*)d_in[1];
    const float*    W1    = (const float*)d_in[2];
    const float*    b1    = (const float*)d_in[3];
    const float*    gamma = (const float*)d_in[4];
    const float*    beta  = (const float*)d_in[5];
    const float*    rmean = (const float*)d_in[6];
    const float*    rvar  = (const float*)d_in[7];
    const float*    W2    = (const float*)d_in[8];
    const float*    b2    = (const float*)d_in[9];

    const int M = in_sizes[0] / DIM;        // 100000
    const int E = in_sizes[1] / 2;          // 1600000
    const size_t hbytes = (size_t)M * DIM * sizeof(float);

    float* out = (float*)d_out;
    char*  ws  = (char*)d_ws;

    // Workspace layout
    size_t o = 0;
    int* flag = (int*)(ws + o);       o = align256(o + 4);
    float* hbuf = (float*)(ws + o);   o = align256(o + hbytes);
    size_t csr_off_base = o;
    int* deg  = (int*)(ws + o);       o = align256(o + (size_t)M * 4);
    int* off  = (int*)(ws + o);       o = align256(o + ((size_t)M + 1) * 4);
    int* pos  = (int*)(ws + o);       o = align256(o + (size_t)M * 4);
    int* bsum = (int*)(ws + o);       o = align256(o + 4096);
    int* bscan= (int*)(ws + o);       o = align256(o + 4096);
    int* csr  = (int*)(ws + o);       o = align256(o + (size_t)E * 4);
    const bool use_csr = (o <= ws_size);   // host-side constant across calls
    (void)csr_off_base;

    detect_idx64<<<1, 64, 0, stream>>>(eidx, flag);

    const int eblocks    = (E + 255) / 256;
    const int nscan      = (M + 255) / 256;
    const int gemm_blocks = (M + 63) / 64;
    const int ls_blocks   = (M * 64 + 255) / 256;
    const int gat_blocks  = (M * 64 + 255) / 256;

    if (use_csr) {
        hipMemsetAsync(deg, 0, (size_t)M * 4, stream);
        hist_dst<<<eblocks, 256, 0, stream>>>(eidx, deg, E, flag);
        scan_block<<<nscan, 256, 0, stream>>>(deg, off, bsum, M);
        scan_sums<<<1, 64, 0, stream>>>(bsum, bscan, nscan);
        scan_add<<<nscan, 256, 0, stream>>>(deg, off, pos, bscan, M);
        fill_csr<<<eblocks, 256, 0, stream>>>(eidx, pos, csr, E, flag);
    }

    float* bufA = hbuf;
    float* bufB = out;
    const float* h = x;

    for (int l = 0; l < 3; ++l) {
        if (use_csr) {
            gather_sum<<<gat_blocks, 256, 0, stream>>>(h, off, csr, bufA, M);
        } else {
            hipMemcpyAsync(bufA, h, hbytes, hipMemcpyDeviceToDevice, stream);
            const int scatter_blocks = (int)(((long long)E * 32 + 255) / 256);
            scatter_add<<<scatter_blocks, 256, 0, stream>>>(eidx, h, bufA, E, flag);
        }
        gemm_fused<<<gemm_blocks, 256, 0, stream>>>(
            bufA, W1 + (size_t)l * DIM * DIM, b1 + (size_t)l * DIM,
            gamma + (size_t)l * DIM, beta + (size_t)l * DIM,
            rmean + (size_t)l * DIM, rvar + (size_t)l * DIM,
            bufB, M, 1);
        gemm_fused<<<gemm_blocks, 256, 0, stream>>>(
            bufB, W2 + (size_t)l * DIM * DIM, b2 + (size_t)l * DIM,
            nullptr, nullptr, nullptr, nullptr,
            bufA, M, 0);
        h = bufA;
        float* tmp = bufA; bufA = bufB; bufB = tmp;
    }
    log_softmax_k<<<ls_blocks, 256, 0, stream>>>(h, out, M);
}

// Round 3
// 882.771 us; speedup vs baseline: 9.9128x; 1.4773x over previous
//
#include <hip/hip_runtime.h>
#include <hip/hip_bf16.h>
#include <cstdint>

#define DIM 128
#define ASTR 136   // LDS row stride (ushorts) for 64-row A/H1 tile: 272 B = 16-B aligned, 2-way banks
#define WSTR 136   // LDS row stride for 128-row Wt tile

typedef __bf16 bf16x8 __attribute__((ext_vector_type(8)));
typedef float  f32x4  __attribute__((ext_vector_type(4)));

__device__ __forceinline__ unsigned short f2bf(float f) {
    union { float f; unsigned u; } x; x.f = f;
    unsigned r = x.u + 0x7fffu + ((x.u >> 16) & 1u);   // RNE
    return (unsigned short)(r >> 16);
}

// ---------------------------------------------------------------------------
__global__ void detect_idx64(const unsigned* __restrict__ e, int* __restrict__ flag) {
    if (threadIdx.x == 0 && blockIdx.x == 0) {
        int is64 = 1;
        for (int i = 0; i < 32; ++i) {
            if (e[2 * i + 1] != 0u) { is64 = 0; break; }
        }
        *flag = is64;
    }
}

__device__ __forceinline__ void load_edge(const unsigned* __restrict__ eidx,
                                          int e, int E, int is64,
                                          int& s, int& d) {
    if (is64) {
        s = (int)eidx[2 * (size_t)e];
        d = (int)eidx[2 * ((size_t)E + (size_t)e)];
    } else {
        s = (int)eidx[(size_t)e];
        d = (int)eidx[(size_t)E + (size_t)e];
    }
}

// ---------------------------- weight prep ----------------------------------
// Wt[l][w][n*128+k] = W_w[l][k*128+n] as bf16 (B^T layout for MFMA B-frags).
__global__ __launch_bounds__(256) void prep_w(
    const float* __restrict__ W1, const float* __restrict__ W2,
    unsigned short* __restrict__ Wt)
{
    int id = blockIdx.x * 256 + threadIdx.x;     // 3*2*16384 = 98304
    if (id >= 3 * 2 * 16384) return;
    int l = id / 32768;
    int r = id - l * 32768;
    int w = r >> 14;
    int idx = r & 16383;
    int k = idx >> 7, n = idx & 127;
    const float* src = (w ? W2 : W1) + (size_t)l * 16384;
    Wt[(size_t)id - idx + ((size_t)n * 128 + k)] = f2bf(src[k * 128 + n]);
}

// affA = gamma*rsqrt(var+eps); affB = (b1-mean)*affA + beta   (flat [3][128])
__global__ void prep_aff(const float* __restrict__ b1, const float* __restrict__ g,
                         const float* __restrict__ be, const float* __restrict__ m,
                         const float* __restrict__ v,
                         float* __restrict__ affA, float* __restrict__ affB)
{
    int id = blockIdx.x * 256 + threadIdx.x;
    if (id >= 3 * DIM) return;
    float A = g[id] * rsqrtf(v[id] + 1e-5f);
    affA[id] = A;
    affB[id] = (b1[id] - m[id]) * A + be[id];
}

// ---------------------------- CSR construction -----------------------------
__global__ __launch_bounds__(256) void hist_dst(
    const unsigned* __restrict__ eidx, int* __restrict__ deg, int E,
    const int* __restrict__ flag)
{
    int e = blockIdx.x * 256 + threadIdx.x;
    if (e >= E) return;
    int s, d;
    load_edge(eidx, e, E, *flag, s, d);
    atomicAdd(&deg[d], 1);
}

__global__ __launch_bounds__(256) void scan_block(
    const int* __restrict__ deg, int* __restrict__ off,
    int* __restrict__ bsum, int N)
{
    __shared__ int sh[256];
    int t = threadIdx.x;
    int i = blockIdx.x * 256 + t;
    int v = (i < N) ? deg[i] : 0;
    sh[t] = v;
    __syncthreads();
    #pragma unroll
    for (int ofs = 1; ofs < 256; ofs <<= 1) {
        int add = (t >= ofs) ? sh[t - ofs] : 0;
        __syncthreads();
        sh[t] += add;
        __syncthreads();
    }
    if (i < N) off[i + 1] = sh[t];
    if (t == 255) bsum[blockIdx.x] = sh[255];
}

__global__ void scan_sums(const int* __restrict__ bsum,
                          int* __restrict__ bscan, int nblk)
{
    if (threadIdx.x == 0 && blockIdx.x == 0) {
        int run = 0;
        for (int b = 0; b < nblk; ++b) { run += bsum[b]; bscan[b] = run; }
    }
}

__global__ __launch_bounds__(256) void scan_add(
    const int* __restrict__ deg, int* __restrict__ off,
    int* __restrict__ pos, const int* __restrict__ bscan, int N)
{
    int i = blockIdx.x * 256 + threadIdx.x;
    if (i == 0) off[0] = 0;
    if (i >= N) return;
    int base = (blockIdx.x > 0) ? bscan[blockIdx.x - 1] : 0;
    int incl = off[i + 1] + base;
    off[i + 1] = incl;
    pos[i] = incl - deg[i];
}

__global__ __launch_bounds__(256) void fill_csr(
    const unsigned* __restrict__ eidx, int* __restrict__ pos,
    int* __restrict__ csr, int E, const int* __restrict__ flag)
{
    int e = blockIdx.x * 256 + threadIdx.x;
    if (e >= E) return;
    int s, d;
    load_edge(eidx, e, E, *flag, s, d);
    int slot = atomicAdd(&pos[d], 1);
    csr[slot] = s;
}

// ---------------------------------------------------------------------------
// CSR gather: AGG[d] = H[d] + sum_{s in N(d)} H[s]. One wave per node.
// 2-deep unroll -> two outstanding row loads per wave.
// ---------------------------------------------------------------------------
__global__ __launch_bounds__(256) void gather_sum(
    const float* __restrict__ H, const int* __restrict__ off,
    const int* __restrict__ csr, float* __restrict__ AGG, int M)
{
    int node = (blockIdx.x * 256 + threadIdx.x) >> 6;
    int lane = threadIdx.x & 63;
    if (node >= M) return;
    int beg = off[node], end = off[node + 1];
    float2 acc = *(const float2*)(H + (size_t)node * DIM + lane * 2);
    float2 acc2 = make_float2(0.f, 0.f);
    int j = beg;
    for (; j + 1 < end; j += 2) {
        int s0 = csr[j], s1 = csr[j + 1];
        float2 v0 = *(const float2*)(H + (size_t)s0 * DIM + lane * 2);
        float2 v1 = *(const float2*)(H + (size_t)s1 * DIM + lane * 2);
        acc.x += v0.x;  acc.y += v0.y;
        acc2.x += v1.x; acc2.y += v1.y;
    }
    if (j < end) {
        int s0 = csr[j];
        float2 v0 = *(const float2*)(H + (size_t)s0 * DIM + lane * 2);
        acc.x += v0.x; acc.y += v0.y;
    }
    acc.x += acc2.x; acc.y += acc2.y;
    *(float2*)(AGG + (size_t)node * DIM + lane * 2) = acc;
}

// ------------------------- Fallback: atomic scatter ------------------------
__global__ __launch_bounds__(256) void scatter_add(
    const unsigned* __restrict__ eidx, const float* __restrict__ H,
    float* __restrict__ AGG, int E, const int* __restrict__ flag)
{
    long long gid = (long long)blockIdx.x * 256 + threadIdx.x;
    int e = (int)(gid >> 5);
    if (e >= E) return;
    int c = (int)(gid & 31);
    int s, d;
    load_edge(eidx, e, E, *flag, s, d);
    float4 v = *(const float4*)(H + (size_t)s * DIM + c * 4);
    float* p = AGG + (size_t)d * DIM + c * 4;
    unsafeAtomicAdd(p + 0, v.x);
    unsafeAtomicAdd(p + 1, v.y);
    unsafeAtomicAdd(p + 2, v.z);
    unsafeAtomicAdd(p + 3, v.w);
}

// ---------------------------------------------------------------------------
// Fused layer: OUT = relu( relu( (AGG@W1+b1 folded-BN) ) @ W2 + b2 )
// Block: 64 rows x 128 cols, 4 waves (wave w owns rows [16w,16w+16)).
// bf16 MFMA 16x16x32; H1 round-trips through the A-tile LDS region
// (D-layout -> A-layout transform); W tile restaged between GEMMs.
// ---------------------------------------------------------------------------
__global__ __launch_bounds__(256) void fused_layer(
    const float* __restrict__ AGG, const unsigned short* __restrict__ W1t,
    const unsigned short* __restrict__ W2t, const float* __restrict__ affA,
    const float* __restrict__ affB, const float* __restrict__ b2,
    float* __restrict__ OUT, int M)
{
    __shared__ unsigned short Asub[64 * ASTR];    // A tile, then H1 tile
    __shared__ unsigned short Wsub[128 * WSTR];   // W1^T, then W2^T
    const int t = threadIdx.x;
    const int row0 = blockIdx.x * 64;
    const int w = t >> 6;
    const int lane = t & 63;
    const int lm = lane & 15;
    const int quad = lane >> 4;

    // --- stage A (fp32 -> bf16), zero-pad OOB rows ---
    #pragma unroll
    for (int i = 0; i < 8; ++i) {
        int idx = t + 256 * i;          // 2048 float4 chunks = 64 rows x 32
        int row = idx >> 5, kc = idx & 31;
        int gr = row0 + row;
        float4 v = make_float4(0.f, 0.f, 0.f, 0.f);
        if (gr < M) v = ((const float4*)(AGG + (size_t)gr * DIM))[kc];
        ushort4 o;
        o.x = f2bf(v.x); o.y = f2bf(v.y); o.z = f2bf(v.z); o.w = f2bf(v.w);
        *(ushort4*)&Asub[row * ASTR + kc * 4] = o;
    }
    // --- stage W1^T (bf16, pre-transposed) ---
    #pragma unroll
    for (int i = 0; i < 16; ++i) {
        int idx = t + 256 * i;          // 4096 ushort4 chunks = 128 rows x 32
        int n = idx >> 5, kc = idx & 31;
        *(ushort4*)&Wsub[n * WSTR + kc * 4] = ((const ushort4*)W1t)[idx];
    }
    __syncthreads();

    const int arow = w * 16 + lm;
    f32x4 acc[8];
    #pragma unroll
    for (int i = 0; i < 8; ++i) { f32x4 z = {0.f, 0.f, 0.f, 0.f}; acc[i] = z; }

    #pragma unroll
    for (int kc = 0; kc < 4; ++kc) {
        int k0 = kc * 32 + quad * 8;
        bf16x8 a = *(const bf16x8*)&Asub[arow * ASTR + k0];
        #pragma unroll
        for (int tt = 0; tt < 8; ++tt) {
            bf16x8 b = *(const bf16x8*)&Wsub[(tt * 16 + lm) * WSTR + k0];
            acc[tt] = __builtin_amdgcn_mfma_f32_16x16x32_bf16(a, b, acc[tt], 0, 0, 0);
        }
    }

    // --- epilogue 1: BN affine + relu, write H1 (bf16) into own Asub rows ---
    #pragma unroll
    for (int tt = 0; tt < 8; ++tt) {
        int c = tt * 16 + lm;
        float aA = affA[c], aB = affB[c];
        #pragma unroll
        for (int r = 0; r < 4; ++r) {
            float h = fmaxf(acc[tt][r] * aA + aB, 0.f);
            Asub[(w * 16 + quad * 4 + r) * ASTR + c] = f2bf(h);
        }
    }
    __syncthreads();                    // all waves done reading W1 tile
    // --- restage W2^T over Wsub ---
    #pragma unroll
    for (int i = 0; i < 16; ++i) {
        int idx = t + 256 * i;
        int n = idx >> 5, kc = idx & 31;
        *(ushort4*)&Wsub[n * WSTR + kc * 4] = ((const ushort4*)W2t)[idx];
    }
    __syncthreads();

    f32x4 acc2[8];
    #pragma unroll
    for (int i = 0; i < 8; ++i) { f32x4 z = {0.f, 0.f, 0.f, 0.f}; acc2[i] = z; }

    #pragma unroll
    for (int kc = 0; kc < 4; ++kc) {
        int k0 = kc * 32 + quad * 8;
        bf16x8 a = *(const bf16x8*)&Asub[arow * ASTR + k0];
        #pragma unroll
        for (int tt = 0; tt < 8; ++tt) {
            bf16x8 b = *(const bf16x8*)&Wsub[(tt * 16 + lm) * WSTR + k0];
            acc2[tt] = __builtin_amdgcn_mfma_f32_16x16x32_bf16(a, b, acc2[tt], 0, 0, 0);
        }
    }

    // --- epilogue 2: +b2, relu, fp32 store ---
    #pragma unroll
    for (int tt = 0; tt < 8; ++tt) {
        int c = tt * 16 + lm;
        float bb = b2[c];
        #pragma unroll
        for (int r = 0; r < 4; ++r) {
            int gr = row0 + w * 16 + quad * 4 + r;
            if (gr < M) {
                OUT[(size_t)gr * DIM + c] = fmaxf(acc2[tt][r] + bb, 0.f);
            }
        }
    }
}

// ---------------------------------------------------------------------------
// In-place row-wise log_softmax, one wave per row.
// ---------------------------------------------------------------------------
__global__ __launch_bounds__(256) void log_softmax_k(
    float* __restrict__ H, int M)
{
    int gid = blockIdx.x * 256 + threadIdx.x;
    int row = gid >> 6;
    int lane = threadIdx.x & 63;
    if (row >= M) return;
    float2 hv = *(const float2*)(H + (size_t)row * DIM + lane * 2);
    float m = fmaxf(hv.x, hv.y);
    #pragma unroll
    for (int off = 32; off > 0; off >>= 1) m = fmaxf(m, __shfl_xor(m, off));
    float s = __expf(hv.x - m) + __expf(hv.y - m);
    #pragma unroll
    for (int off = 32; off > 0; off >>= 1) s += __shfl_xor(s, off);
    float lse = m + __logf(s);
    float2 o;
    o.x = hv.x - lse;
    o.y = hv.y - lse;
    *(float2*)(H + (size_t)row * DIM + lane * 2) = o;
}

// ---------------------------------------------------------------------------
static inline size_t align256(size_t v) { return (v + 255) & ~(size_t)255; }

extern "C" void kernel_launch(void* const* d_in, const int* in_sizes, int n_in,
                              void* d_out, int out_size, void* d_ws, size_t ws_size,
                              hipStream_t stream) {
    const float*    x     = (const float*)d_in[0];
    const unsigned* eidx  = (const unsigned*)d_in[1];
    const float*    W1    = (const float*)d_in[2];
    const float*    b1    = (const float*)d_in[3];
    const float*    gamma = (const float*)d_in[4];
    const float*    beta  = (const float*)d_in[5];
    const float*    rmean = (const float*)d_in[6];
    const float*    rvar  = (const float*)d_in[7];
    const float*    W2    = (const float*)d_in[8];
    const float*    b2    = (const float*)d_in[9];

    const int M = in_sizes[0] / DIM;        // 100000
    const int E = in_sizes[1] / 2;          // 1600000
    const size_t hbytes = (size_t)M * DIM * sizeof(float);

    float* out = (float*)d_out;
    char*  ws  = (char*)d_ws;

    // Workspace layout
    size_t o = 0;
    int* flag = (int*)(ws + o);                 o = align256(o + 4);
    unsigned short* Wt = (unsigned short*)(ws + o); o = align256(o + (size_t)3 * 2 * 16384 * 2);
    float* affA = (float*)(ws + o);             o = align256(o + 3 * DIM * 4);
    float* affB = (float*)(ws + o);             o = align256(o + 3 * DIM * 4);
    float* hbuf = (float*)(ws + o);             o = align256(o + hbytes);
    int* deg  = (int*)(ws + o);                 o = align256(o + (size_t)M * 4);
    int* off  = (int*)(ws + o);                 o = align256(o + ((size_t)M + 1) * 4);
    int* pos  = (int*)(ws + o);                 o = align256(o + (size_t)M * 4);
    int* bsum = (int*)(ws + o);                 o = align256(o + 4096);
    int* bscan= (int*)(ws + o);                 o = align256(o + 4096);
    int* csr  = (int*)(ws + o);                 o = align256(o + (size_t)E * 4);
    const bool use_csr = (o <= ws_size);

    detect_idx64<<<1, 64, 0, stream>>>(eidx, flag);
    prep_w<<<(3 * 2 * 16384 + 255) / 256, 256, 0, stream>>>(W1, W2, Wt);
    prep_aff<<<2, 256, 0, stream>>>(b1, gamma, beta, rmean, rvar, affA, affB);

    const int eblocks     = (E + 255) / 256;
    const int nscan       = (M + 255) / 256;
    const int fuse_blocks = (M + 63) / 64;
    const int ls_blocks   = (M * 64 + 255) / 256;
    const int gat_blocks  = (M * 64 + 255) / 256;

    if (use_csr) {
        hipMemsetAsync(deg, 0, (size_t)M * 4, stream);
        hist_dst<<<eblocks, 256, 0, stream>>>(eidx, deg, E, flag);
        scan_block<<<nscan, 256, 0, stream>>>(deg, off, bsum, M);
        scan_sums<<<1, 64, 0, stream>>>(bsum, bscan, nscan);
        scan_add<<<nscan, 256, 0, stream>>>(deg, off, pos, bscan, M);
        fill_csr<<<eblocks, 256, 0, stream>>>(eidx, pos, csr, E, flag);
    }

    const float* h = x;
    for (int l = 0; l < 3; ++l) {
        if (use_csr) {
            gather_sum<<<gat_blocks, 256, 0, stream>>>(h, off, csr, hbuf, M);
        } else {
            hipMemcpyAsync(hbuf, h, hbytes, hipMemcpyDeviceToDevice, stream);
            const int scatter_blocks = (int)(((long long)E * 32 + 255) / 256);
            scatter_add<<<scatter_blocks, 256, 0, stream>>>(eidx, h, hbuf, E, flag);
        }
        fused_layer<<<fuse_blocks, 256, 0, stream>>>(
            hbuf,
            Wt + ((size_t)l * 2 + 0) * 16384,
            Wt + ((size_t)l * 2 + 1) * 16384,
            affA + (size_t)l * DIM, affB + (size_t)l * DIM,
            b2 + (size_t)l * DIM,
            out, M);
        h = out;
    }
    log_softmax_k<<<ls_blocks, 256, 0, stream>>>(out, M);
}

// Round 4
// 678.726 us; speedup vs baseline: 12.8929x; 1.3006x over previous
//
#include <hip/hip_runtime.h>
#include <hip/hip_bf16.h>
#include <cstdint>

#define DIM 128
#define ASTR 136   // LDS row stride (ushorts): 272 B, 16-B aligned, 2-way banks (free)
#define WSTR 136

typedef __bf16 bf16x8 __attribute__((ext_vector_type(8)));
typedef float  f32x4  __attribute__((ext_vector_type(4)));
typedef unsigned short u16x8 __attribute__((ext_vector_type(8)));
typedef unsigned short u16x4 __attribute__((ext_vector_type(4)));

__device__ __forceinline__ unsigned short f2bf(float f) {
    union { float f; unsigned u; } x; x.f = f;
    unsigned r = x.u + 0x7fffu + ((x.u >> 16) & 1u);   // RNE
    return (unsigned short)(r >> 16);
}
__device__ __forceinline__ float2 bfpair2f(unsigned v) {
    union { unsigned u; float f; } a, b;
    a.u = (v & 0xffffu) << 16;
    b.u = v & 0xffff0000u;
    return make_float2(a.f, b.f);
}

// ---------------------------------------------------------------------------
__global__ void detect_idx64(const unsigned* __restrict__ e, int* __restrict__ flag) {
    if (threadIdx.x == 0 && blockIdx.x == 0) {
        int is64 = 1;
        for (int i = 0; i < 32; ++i) {
            if (e[2 * i + 1] != 0u) { is64 = 0; break; }
        }
        *flag = is64;
    }
}

__device__ __forceinline__ void load_edge(const unsigned* __restrict__ eidx,
                                          int e, int E, int is64,
                                          int& s, int& d) {
    if (is64) {
        s = (int)eidx[2 * (size_t)e];
        d = (int)eidx[2 * ((size_t)E + (size_t)e)];
    } else {
        s = (int)eidx[(size_t)e];
        d = (int)eidx[(size_t)E + (size_t)e];
    }
}

// ---------------------------- prep kernels ---------------------------------
// Wt[l][w][n*128+k] = W_w[l][k*128+n] as bf16 (B^T layout for MFMA B-frags).
__global__ __launch_bounds__(256) void prep_w(
    const float* __restrict__ W1, const float* __restrict__ W2,
    unsigned short* __restrict__ Wt)
{
    int id = blockIdx.x * 256 + threadIdx.x;     // 3*2*16384 = 98304
    if (id >= 3 * 2 * 16384) return;
    int l = id / 32768;
    int r = id - l * 32768;
    int w = r >> 14;
    int idx = r & 16383;
    int k = idx >> 7, n = idx & 127;
    const float* src = (w ? W2 : W1) + (size_t)l * 16384;
    Wt[(size_t)id - idx + ((size_t)n * 128 + k)] = f2bf(src[k * 128 + n]);
}

__global__ void prep_aff(const float* __restrict__ b1, const float* __restrict__ g,
                         const float* __restrict__ be, const float* __restrict__ m,
                         const float* __restrict__ v,
                         float* __restrict__ affA, float* __restrict__ affB)
{
    int id = blockIdx.x * 256 + threadIdx.x;
    if (id >= 3 * DIM) return;
    float A = g[id] * rsqrtf(v[id] + 1e-5f);
    affA[id] = A;
    affB[id] = (b1[id] - m[id]) * A + be[id];
}

// fp32 -> bf16 bulk convert (x -> xbf)
__global__ __launch_bounds__(256) void x2bf(
    const float4* __restrict__ X, u16x4* __restrict__ O, int n4)
{
    int id = blockIdx.x * 256 + threadIdx.x;
    if (id >= n4) return;
    float4 v = X[id];
    u16x4 o;
    o[0] = f2bf(v.x); o[1] = f2bf(v.y); o[2] = f2bf(v.z); o[3] = f2bf(v.w);
    O[id] = o;
}

// ---------------------------- CSR construction -----------------------------
__global__ __launch_bounds__(256) void hist_dst(
    const unsigned* __restrict__ eidx, int* __restrict__ deg, int E,
    const int* __restrict__ flag)
{
    int e = blockIdx.x * 256 + threadIdx.x;
    if (e >= E) return;
    int s, d;
    load_edge(eidx, e, E, *flag, s, d);
    atomicAdd(&deg[d], 1);
}

__global__ __launch_bounds__(256) void scan_block(
    const int* __restrict__ deg, int* __restrict__ off,
    int* __restrict__ bsum, int N)
{
    __shared__ int sh[256];
    int t = threadIdx.x;
    int i = blockIdx.x * 256 + t;
    int v = (i < N) ? deg[i] : 0;
    sh[t] = v;
    __syncthreads();
    #pragma unroll
    for (int ofs = 1; ofs < 256; ofs <<= 1) {
        int add = (t >= ofs) ? sh[t - ofs] : 0;
        __syncthreads();
        sh[t] += add;
        __syncthreads();
    }
    if (i < N) off[i + 1] = sh[t];
    if (t == 255) bsum[blockIdx.x] = sh[255];
}

__global__ void scan_sums(const int* __restrict__ bsum,
                          int* __restrict__ bscan, int nblk)
{
    if (threadIdx.x == 0 && blockIdx.x == 0) {
        int run = 0;
        for (int b = 0; b < nblk; ++b) { run += bsum[b]; bscan[b] = run; }
    }
}

__global__ __launch_bounds__(256) void scan_add(
    const int* __restrict__ deg, int* __restrict__ off,
    int* __restrict__ pos, const int* __restrict__ bscan, int N)
{
    int i = blockIdx.x * 256 + threadIdx.x;
    if (i == 0) off[0] = 0;
    if (i >= N) return;
    int base = (blockIdx.x > 0) ? bscan[blockIdx.x - 1] : 0;
    int incl = off[i + 1] + base;
    off[i + 1] = incl;
    pos[i] = incl - deg[i];
}

__global__ __launch_bounds__(256) void fill_csr(
    const unsigned* __restrict__ eidx, int* __restrict__ pos,
    int* __restrict__ csr, int E, const int* __restrict__ flag)
{
    int e = blockIdx.x * 256 + threadIdx.x;
    if (e >= E) return;
    int s, d;
    load_edge(eidx, e, E, *flag, s, d);
    int slot = atomicAdd(&pos[d], 1);
    csr[slot] = s;
}

// ---------------------------------------------------------------------------
// bf16 CSR gather: AGG[d] = H[d] + sum_{s in N(d)} H[s]. One wave per node,
// one 4-B (2×bf16) load per lane per row; fp32 accumulate; bf16 write.
// 4-deep unroll -> 4 outstanding row loads per wave.
// ---------------------------------------------------------------------------
__global__ __launch_bounds__(256) void gather_bf(
    const unsigned* __restrict__ H,   // bf16 pairs, row stride 64 words
    const int* __restrict__ off, const int* __restrict__ csr,
    unsigned* __restrict__ AGG, int M)
{
    int node = (blockIdx.x * 256 + threadIdx.x) >> 6;
    int lane = threadIdx.x & 63;
    if (node >= M) return;
    int beg = off[node], end = off[node + 1];

    float2 a0 = bfpair2f(H[(size_t)node * 64 + lane]);
    float2 a1 = make_float2(0.f, 0.f);
    float2 a2 = make_float2(0.f, 0.f);
    float2 a3 = make_float2(0.f, 0.f);

    int j = beg;
    for (; j + 3 < end; j += 4) {
        int s0 = csr[j], s1 = csr[j + 1], s2 = csr[j + 2], s3 = csr[j + 3];
        unsigned w0 = H[(size_t)s0 * 64 + lane];
        unsigned w1 = H[(size_t)s1 * 64 + lane];
        unsigned w2 = H[(size_t)s2 * 64 + lane];
        unsigned w3 = H[(size_t)s3 * 64 + lane];
        float2 v0 = bfpair2f(w0), v1 = bfpair2f(w1);
        float2 v2 = bfpair2f(w2), v3 = bfpair2f(w3);
        a0.x += v0.x; a0.y += v0.y;
        a1.x += v1.x; a1.y += v1.y;
        a2.x += v2.x; a2.y += v2.y;
        a3.x += v3.x; a3.y += v3.y;
    }
    for (; j < end; ++j) {
        float2 v = bfpair2f(H[(size_t)csr[j] * 64 + lane]);
        a0.x += v.x; a0.y += v.y;
    }
    a0.x += a1.x + a2.x + a3.x;
    a0.y += a1.y + a2.y + a3.y;
    AGG[(size_t)node * 64 + lane] =
        (unsigned)f2bf(a0.x) | ((unsigned)f2bf(a0.y) << 16);
}

// ---------------------------------------------------------------------------
// Fused layer: OUT = relu( relu( (AGG@W1 + b1, folded BN) ) @ W2 + b2 )
// Block: 64 rows x 128 cols, 4 waves. bf16 MFMA 16x16x32.
// AGG arrives bf16 (direct LDS copy). BF_OUT: bf16 h out, else fp32.
// ---------------------------------------------------------------------------
template<int BF_OUT>
__global__ __launch_bounds__(256) void fused_layer(
    const unsigned short* __restrict__ AGGb,
    const unsigned short* __restrict__ W1t,
    const unsigned short* __restrict__ W2t,
    const float* __restrict__ affA, const float* __restrict__ affB,
    const float* __restrict__ b2, void* __restrict__ OUTp, int M)
{
    __shared__ unsigned short Asub[64 * ASTR];
    __shared__ unsigned short Wsub[128 * WSTR];
    const int t = threadIdx.x;
    const int row0 = blockIdx.x * 64;
    const int w = t >> 6;
    const int lane = t & 63;
    const int lm = lane & 15;
    const int quad = lane >> 4;

    // --- stage A (bf16 direct), zero-pad OOB rows ---
    #pragma unroll
    for (int i = 0; i < 8; ++i) {
        int idx = t + 256 * i;          // 2048 chunks of 8 ushorts
        int row = idx >> 4, ch = idx & 15;
        int gr = row0 + row;
        u16x8 v = {0, 0, 0, 0, 0, 0, 0, 0};
        if (gr < M) v = ((const u16x8*)(AGGb + (size_t)gr * DIM))[ch];
        *(u16x8*)&Asub[row * ASTR + ch * 8] = v;
    }
    // --- stage W1^T ---
    #pragma unroll
    for (int i = 0; i < 16; ++i) {
        int idx = t + 256 * i;          // 4096 ushort4 chunks
        int n = idx >> 5, kc = idx & 31;
        *(ushort4*)&Wsub[n * WSTR + kc * 4] = ((const ushort4*)W1t)[idx];
    }
    __syncthreads();

    const int arow = w * 16 + lm;
    f32x4 acc[8];
    #pragma unroll
    for (int i = 0; i < 8; ++i) { f32x4 z = {0.f, 0.f, 0.f, 0.f}; acc[i] = z; }

    #pragma unroll
    for (int kc = 0; kc < 4; ++kc) {
        int k0 = kc * 32 + quad * 8;
        bf16x8 a = *(const bf16x8*)&Asub[arow * ASTR + k0];
        #pragma unroll
        for (int tt = 0; tt < 8; ++tt) {
            bf16x8 b = *(const bf16x8*)&Wsub[(tt * 16 + lm) * WSTR + k0];
            acc[tt] = __builtin_amdgcn_mfma_f32_16x16x32_bf16(a, b, acc[tt], 0, 0, 0);
        }
    }

    // --- epilogue 1: BN affine + relu, H1 (bf16) back into Asub ---
    #pragma unroll
    for (int tt = 0; tt < 8; ++tt) {
        int c = tt * 16 + lm;
        float aA = affA[c], aB = affB[c];
        #pragma unroll
        for (int r = 0; r < 4; ++r) {
            float h = fmaxf(acc[tt][r] * aA + aB, 0.f);
            Asub[(w * 16 + quad * 4 + r) * ASTR + c] = f2bf(h);
        }
    }
    __syncthreads();
    // --- restage W2^T ---
    #pragma unroll
    for (int i = 0; i < 16; ++i) {
        int idx = t + 256 * i;
        int n = idx >> 5, kc = idx & 31;
        *(ushort4*)&Wsub[n * WSTR + kc * 4] = ((const ushort4*)W2t)[idx];
    }
    __syncthreads();

    f32x4 acc2[8];
    #pragma unroll
    for (int i = 0; i < 8; ++i) { f32x4 z = {0.f, 0.f, 0.f, 0.f}; acc2[i] = z; }

    #pragma unroll
    for (int kc = 0; kc < 4; ++kc) {
        int k0 = kc * 32 + quad * 8;
        bf16x8 a = *(const bf16x8*)&Asub[arow * ASTR + k0];
        #pragma unroll
        for (int tt = 0; tt < 8; ++tt) {
            bf16x8 b = *(const bf16x8*)&Wsub[(tt * 16 + lm) * WSTR + k0];
            acc2[tt] = __builtin_amdgcn_mfma_f32_16x16x32_bf16(a, b, acc2[tt], 0, 0, 0);
        }
    }

    // --- epilogue 2: +b2, relu, store ---
    #pragma unroll
    for (int tt = 0; tt < 8; ++tt) {
        int c = tt * 16 + lm;
        float bb = b2[c];
        #pragma unroll
        for (int r = 0; r < 4; ++r) {
            int gr = row0 + w * 16 + quad * 4 + r;
            if (gr < M) {
                float val = fmaxf(acc2[tt][r] + bb, 0.f);
                if (BF_OUT) {
                    ((unsigned short*)OUTp)[(size_t)gr * DIM + c] = f2bf(val);
                } else {
                    ((float*)OUTp)[(size_t)gr * DIM + c] = val;
                }
            }
        }
    }
}

// ---------------------------------------------------------------------------
__global__ __launch_bounds__(256) void log_softmax_k(
    float* __restrict__ H, int M)
{
    int gid = blockIdx.x * 256 + threadIdx.x;
    int row = gid >> 6;
    int lane = threadIdx.x & 63;
    if (row >= M) return;
    float2 hv = *(const float2*)(H + (size_t)row * DIM + lane * 2);
    float m = fmaxf(hv.x, hv.y);
    #pragma unroll
    for (int off = 32; off > 0; off >>= 1) m = fmaxf(m, __shfl_xor(m, off));
    float s = __expf(hv.x - m) + __expf(hv.y - m);
    #pragma unroll
    for (int off = 32; off > 0; off >>= 1) s += __shfl_xor(s, off);
    float lse = m + __logf(s);
    float2 o;
    o.x = hv.x - lse;
    o.y = hv.y - lse;
    *(float2*)(H + (size_t)row * DIM + lane * 2) = o;
}

// ---------------------------------------------------------------------------
static inline size_t align256(size_t v) { return (v + 255) & ~(size_t)255; }

extern "C" void kernel_launch(void* const* d_in, const int* in_sizes, int n_in,
                              void* d_out, int out_size, void* d_ws, size_t ws_size,
                              hipStream_t stream) {
    const float*    x     = (const float*)d_in[0];
    const unsigned* eidx  = (const unsigned*)d_in[1];
    const float*    W1    = (const float*)d_in[2];
    const float*    b1    = (const float*)d_in[3];
    const float*    gamma = (const float*)d_in[4];
    const float*    beta  = (const float*)d_in[5];
    const float*    rmean = (const float*)d_in[6];
    const float*    rvar  = (const float*)d_in[7];
    const float*    W2    = (const float*)d_in[8];
    const float*    b2    = (const float*)d_in[9];

    const int M = in_sizes[0] / DIM;        // 100000
    const int E = in_sizes[1] / 2;          // 1600000
    const size_t hbf_bytes = (size_t)M * DIM * 2;   // bf16 h buffer

    float* out = (float*)d_out;
    char*  ws  = (char*)d_ws;

    // Workspace layout (~59 MB; R2/R3 confirmed ws_size >= ~60 MB)
    size_t o = 0;
    int* flag = (int*)(ws + o);                     o = align256(o + 4);
    unsigned short* Wt = (unsigned short*)(ws + o); o = align256(o + (size_t)3 * 2 * 16384 * 2);
    float* affA = (float*)(ws + o);                 o = align256(o + 3 * DIM * 4);
    float* affB = (float*)(ws + o);                 o = align256(o + 3 * DIM * 4);
    unsigned short* B0 = (unsigned short*)(ws + o); o = align256(o + hbf_bytes);
    unsigned short* AG = (unsigned short*)(ws + o); o = align256(o + hbf_bytes);
    int* deg  = (int*)(ws + o);                     o = align256(o + (size_t)M * 4);
    int* off  = (int*)(ws + o);                     o = align256(o + ((size_t)M + 1) * 4);
    int* pos  = (int*)(ws + o);                     o = align256(o + (size_t)M * 4);
    int* bsum = (int*)(ws + o);                     o = align256(o + 4096);
    int* bscan= (int*)(ws + o);                     o = align256(o + 4096);
    int* csr  = (int*)(ws + o);                     o = align256(o + (size_t)E * 4);

    // Second bf16 ping-pong buffer aliases d_out storage (fp32 final write
    // happens only in layer 2, after the last read of B1 in layer 1's gather).
    unsigned short* B1 = (unsigned short*)d_out;

    detect_idx64<<<1, 64, 0, stream>>>(eidx, flag);
    prep_w<<<(3 * 2 * 16384 + 255) / 256, 256, 0, stream>>>(W1, W2, Wt);
    prep_aff<<<2, 256, 0, stream>>>(b1, gamma, beta, rmean, rvar, affA, affB);
    x2bf<<<(M * 32 + 255) / 256, 256, 0, stream>>>(
        (const float4*)x, (u16x4*)B0, M * 32);

    const int eblocks     = (E + 255) / 256;
    const int nscan       = (M + 255) / 256;
    const int fuse_blocks = (M + 63) / 64;
    const int ls_blocks   = (M * 64 + 255) / 256;
    const int gat_blocks  = (M * 64 + 255) / 256;

    hipMemsetAsync(deg, 0, (size_t)M * 4, stream);
    hist_dst<<<eblocks, 256, 0, stream>>>(eidx, deg, E, flag);
    scan_block<<<nscan, 256, 0, stream>>>(deg, off, bsum, M);
    scan_sums<<<1, 64, 0, stream>>>(bsum, bscan, nscan);
    scan_add<<<nscan, 256, 0, stream>>>(deg, off, pos, bscan, M);
    fill_csr<<<eblocks, 256, 0, stream>>>(eidx, pos, csr, E, flag);

    // Layer 0: B0 -> AG -> B1 (bf16)
    gather_bf<<<gat_blocks, 256, 0, stream>>>((const unsigned*)B0, off, csr,
                                              (unsigned*)AG, M);
    fused_layer<1><<<fuse_blocks, 256, 0, stream>>>(
        AG, Wt + 0 * 16384, Wt + 1 * 16384,
        affA + 0 * DIM, affB + 0 * DIM, b2 + 0 * DIM, (void*)B1, M);
    // Layer 1: B1 -> AG -> B0 (bf16)
    gather_bf<<<gat_blocks, 256, 0, stream>>>((const unsigned*)B1, off, csr,
                                              (unsigned*)AG, M);
    fused_layer<1><<<fuse_blocks, 256, 0, stream>>>(
        AG, Wt + 2 * 16384, Wt + 3 * 16384,
        affA + 1 * DIM, affB + 1 * DIM, b2 + 1 * DIM, (void*)B0, M);
    // Layer 2: B0 -> AG -> out (fp32)
    gather_bf<<<gat_blocks, 256, 0, stream>>>((const unsigned*)B0, off, csr,
                                              (unsigned*)AG, M);
    fused_layer<0><<<fuse_blocks, 256, 0, stream>>>(
        AG, Wt + 4 * 16384, Wt + 5 * 16384,
        affA + 2 * DIM, affB + 2 * DIM, b2 + 2 * DIM, (void*)out, M);

    log_softmax_k<<<ls_blocks, 256, 0, stream>>>(out, M);
}